// Round 9
// baseline (239.717 us; speedup 1.0000x reference)
//
#include <hip/hip_runtime.h>

#define BATCH 16
#define HI 384
#define WI 384
#define CH 32
#define OUT_H 384
#define OUT_W 384
#define HW (HI * WI)
#define NBLK 128                       // partial-sum blocks per batch image

#define TILE_W 12
#define TILE_H 8
#define PASSES 3                       // 96 px / 32 px-per-pass
#define TILES_X (OUT_W / TILE_W)       // 32
#define TILES_Y (OUT_H / TILE_H)       // 48
#define TILES_PER_IMG (TILES_X * TILES_Y)   // 1536
#define SAMP_BLOCKS (BATCH * TILES_PER_IMG) // 24576, divisible by 8

#define MAXPX 224                      // staged-bbox pixel budget
#define PXSTRIDE (MAXPX + 2)           // 226 slots; 226*16B=904 words = 8 mod 32

typedef float f32x4 __attribute__((ext_vector_type(4)));

// ---------------------------------------------------------------------------
// Kernel 1: per-(batch, slice) partial sums (mean pass). No atomics,
// deterministic; 1KB contiguous per wave-iteration; 8 blocks/CU.
// Normal (cache-allocating) loads on purpose: leaves X warm in L3 for the
// gather phase (round-5 counters: gather HBM fetch only ~141MB).
// ---------------------------------------------------------------------------
__global__ __launch_bounds__(256) void k_partial_sums(
    const float* __restrict__ X, float* __restrict__ partials) {
  const int blk = blockIdx.x;  // [0, BATCH*NBLK)
  const int b = blk / NBLK;
  const int sub = blk % NBLK;
  const int t = threadIdx.x;
  const int c4 = t & 7;
  const int poff = t >> 3;     // 0..31
  const int ppb = HW / NBLK;   // 1152
  const int p0 = sub * ppb;

  const f32x4* base = (const f32x4*)(X + (size_t)b * HW * CH);
  f32x4 acc = {0.f, 0.f, 0.f, 0.f};
#pragma unroll 4
  for (int p = p0 + poff; p < p0 + ppb; p += 32) {
    acc += base[(size_t)p * 8 + c4];
  }

  __shared__ f32x4 sh[256];
  sh[t] = acc;
  __syncthreads();
  if (t < 8) {
    f32x4 s = {0.f, 0.f, 0.f, 0.f};
    for (int i = 0; i < 32; ++i) s += sh[i * 8 + t];
    ((f32x4*)(partials + (size_t)blk * CH))[t] = s;
  }
}

// ---------------------------------------------------------------------------
// Kernel 2: reduce partials -> feat [B,32], then theta = feat@W + b.
// ---------------------------------------------------------------------------
__global__ __launch_bounds__(512) void k_theta(
    const float* __restrict__ partials, const float* __restrict__ Wl,
    const float* __restrict__ bl, float* __restrict__ theta) {
  __shared__ float feat[BATCH * CH];  // 512
  const int t = threadIdx.x;
  {
    const int b = t >> 5, c = t & 31;
    float s = 0.f;
#pragma unroll 8
    for (int i = 0; i < NBLK; ++i)
      s += partials[((size_t)b * NBLK + i) * CH + c];
    feat[t] = s * (1.0f / (float)HW);
  }
  __syncthreads();
  if (t < BATCH * 6) {
    const int b = t / 6, j = t % 6;
    float s = bl[j];
    for (int c = 0; c < CH; ++c) s += feat[b * CH + c] * Wl[c * 6 + j];
    theta[t] = s;
  }
}

// ---------------------------------------------------------------------------
// Kernel 3: affine grid + bilinear sample with LDS TAP DEDUPLICATION.
// Block = 12x8 output tile (96 px, 3 passes of 32 px, 8 threads/px).
// The tile's input footprint bbox is computed from the affine transform of
// the tile's 4 corners (affine is monotone -> extremes at corners; +-1 px
// guard absorbs FP rounding). The bbox rows are staged ONCE into LDS with
// contiguous loads (~2x fewer global request bytes than 4-tap direct
// gather), then all 4 bilinear taps are read from LDS (69 TB/s).
// LDS layout [c4][px] with PXSTRIDE padding: c4-plane starts at bank
// offsets 0,8,16,24,... -> structural-minimum LDS throughput for b128.
// Fallback: if bbox > MAXPX (theta is data-dependent; never hit for the
// mild transforms here), block-uniform direct-gather path (round-7 code).
// Math matches reference exactly: floor -> weights from unclipped fracs,
// indices clipped to [0, 383].
// ---------------------------------------------------------------------------
__device__ __forceinline__ void map_xy(float th0, float th1, float th2,
                                       float th3, float th4, float th5,
                                       int ox, int oy, float& x, float& y) {
  const float gx = fmaf((float)ox, 2.0f / (float)(OUT_W - 1), -1.0f);
  const float gy = fmaf((float)oy, 2.0f / (float)(OUT_H - 1), -1.0f);
  const float sx = th0 * gx + th1 * gy + th2;
  const float sy = th3 * gx + th4 * gy + th5;
  x = (sx + 1.0f) * 0.5f * (float)(WI - 1);
  y = (sy + 1.0f) * 0.5f * (float)(HI - 1);
}

__global__ __launch_bounds__(256) void k_sample(
    const float* __restrict__ X, const float* __restrict__ theta,
    float* __restrict__ out) {
  // bijective XCD swizzle (gridDim.x = 24576, divisible by 8)
  const int q = SAMP_BLOCKS >> 3;
  const int bid = blockIdx.x;
  const int blk = (bid & 7) * q + (bid >> 3);

  const int b = blk / TILES_PER_IMG;
  const int tl = blk % TILES_PER_IMG;
  const int tx = tl / TILES_Y;  // column-major: consecutive blk -> ty+1
  const int ty = tl % TILES_Y;
  const int ox0 = tx * TILE_W;
  const int oy0 = ty * TILE_H;

  const float th0 = theta[b * 6 + 0], th1 = theta[b * 6 + 1],
              th2 = theta[b * 6 + 2], th3 = theta[b * 6 + 3],
              th4 = theta[b * 6 + 4], th5 = theta[b * 6 + 5];

  // ---- tile footprint bbox from the 4 output-tile corners ----
  float xa, ya, xb, yb, xc, yc, xd, yd;
  map_xy(th0, th1, th2, th3, th4, th5, ox0, oy0, xa, ya);
  map_xy(th0, th1, th2, th3, th4, th5, ox0 + TILE_W - 1, oy0, xb, yb);
  map_xy(th0, th1, th2, th3, th4, th5, ox0, oy0 + TILE_H - 1, xc, yc);
  map_xy(th0, th1, th2, th3, th4, th5, ox0 + TILE_W - 1, oy0 + TILE_H - 1, xd, yd);
  const float xminf = fminf(fminf(xa, xb), fminf(xc, xd));
  const float xmaxf = fmaxf(fmaxf(xa, xb), fmaxf(xc, xd));
  const float yminf = fminf(fminf(ya, yb), fminf(yc, yd));
  const float ymaxf = fmaxf(fmaxf(ya, yb), fmaxf(yc, yd));
  const int ixmin = min(max((int)floorf(xminf) - 1, 0), WI - 1);
  const int ixmax = min(max((int)floorf(xmaxf) + 2, 0), WI - 1);
  const int iymin = min(max((int)floorf(yminf) - 1, 0), HI - 1);
  const int iymax = min(max((int)floorf(ymaxf) + 2, 0), HI - 1);
  const int W = ixmax - ixmin + 1;
  const int H = iymax - iymin + 1;
  const bool staged = (W * H <= MAXPX);  // block-uniform

  __shared__ f32x4 lds[8 * PXSTRIDE];  // 28.9 KB -> 5 blocks/CU

  const int t = threadIdx.x;
  const int c4 = t & 7;
  const int lane_px = t >> 3;  // 0..31
  const f32x4* img = (const f32x4*)(X + (size_t)b * HW * CH);

  if (staged) {
    // stage bbox rows: contiguous W*128B segments per row
    for (int r = 0; r < H; ++r) {
      for (int cc = lane_px; cc < W; cc += 32) {
        lds[c4 * PXSTRIDE + r * W + cc] =
            img[((size_t)(iymin + r) * WI + (ixmin + cc)) * 8 + c4];
      }
    }
    __syncthreads();
  }

  const size_t obase = (size_t)b * (OUT_H * OUT_W);
#pragma unroll
  for (int p = 0; p < PASSES; ++p) {
    const int pi = p * 32 + lane_px;
    const int col = pi % TILE_W;  // compile-time divisor
    const int row = pi / TILE_W;
    const int ox = ox0 + col;
    const int oy = oy0 + row;

    float x, y;
    map_xy(th0, th1, th2, th3, th4, th5, ox, oy, x, y);

    const float x0f = floorf(x), y0f = floorf(y);
    const float wx1 = x - x0f, wx0 = 1.0f - wx1;
    const float wy1 = y - y0f, wy0 = 1.0f - wy1;
    const int x0 = min(max((int)x0f, 0), WI - 1);
    const int x1 = min(max((int)x0f + 1, 0), WI - 1);
    const int y0 = min(max((int)y0f, 0), HI - 1);
    const int y1 = min(max((int)y0f + 1, 0), HI - 1);

    f32x4 g00, g01, g10, g11;
    if (staged) {
      const int r0 = (y0 - iymin) * W - ixmin;
      const int r1 = (y1 - iymin) * W - ixmin;
      g00 = lds[c4 * PXSTRIDE + r0 + x0];
      g01 = lds[c4 * PXSTRIDE + r0 + x1];
      g10 = lds[c4 * PXSTRIDE + r1 + x0];
      g11 = lds[c4 * PXSTRIDE + r1 + x1];
    } else {
      g00 = img[((size_t)y0 * WI + x0) * 8 + c4];
      g01 = img[((size_t)y0 * WI + x1) * 8 + c4];
      g10 = img[((size_t)y1 * WI + x0) * 8 + c4];
      g11 = img[((size_t)y1 * WI + x1) * 8 + c4];
    }

    const float w00 = wy0 * wx0, w01 = wy0 * wx1;
    const float w10 = wy1 * wx0, w11 = wy1 * wx1;
    const f32x4 r = g00 * w00 + g01 * w01 + g10 * w10 + g11 * w11;

    const size_t n = (obase + (size_t)oy * OUT_W + ox) * 8 + c4;
    __builtin_nontemporal_store(r, (f32x4*)out + n);
  }
}

extern "C" void kernel_launch(void* const* d_in, const int* in_sizes, int n_in,
                              void* d_out, int out_size, void* d_ws,
                              size_t ws_size, hipStream_t stream) {
  const float* X = (const float*)d_in[0];
  const float* Wl = (const float*)d_in[1];
  const float* bl = (const float*)d_in[2];
  float* out = (float*)d_out;

  float* partials = (float*)d_ws;                       // BATCH*NBLK*CH floats
  float* theta = partials + (size_t)BATCH * NBLK * CH;  // BATCH*6 floats

  k_partial_sums<<<BATCH * NBLK, 256, 0, stream>>>(X, partials);
  k_theta<<<1, 512, 0, stream>>>(partials, Wl, bl, theta);
  k_sample<<<SAMP_BLOCKS, 256, 0, stream>>>(X, theta, out);
}

// Round 10
// 182.664 us; speedup vs baseline: 1.3123x; 1.3123x over previous
//
#include <hip/hip_runtime.h>

#define BATCH 16
#define HI 384
#define WI 384
#define CH 32
#define OUT_H 384
#define OUT_W 384
#define HW (HI * WI)
#define NBLK 128                       // partial-sum blocks per batch image
#define TILE_W 8
#define TILE_H 4
#define TILES_X (OUT_W / TILE_W)       // 48
#define TILES_Y (OUT_H / TILE_H)       // 96
#define TILES_PER_IMG (TILES_X * TILES_Y)       // 4608
#define SAMP_BLOCKS (BATCH * TILES_PER_IMG)     // 73728, divisible by 8

typedef float f32x4 __attribute__((ext_vector_type(4)));

// ---------------------------------------------------------------------------
// Kernel 1: per-(batch, slice) partial sums (mean pass). No atomics,
// deterministic; 1KB contiguous per wave-iteration; 8 blocks/CU.
// Normal (cache-allocating) loads on purpose: leaves X warm in L2/L3 for the
// gather phase (round-5/9 counters: gather HBM fetch only ~147MB).
// ---------------------------------------------------------------------------
__global__ __launch_bounds__(256) void k_partial_sums(
    const float* __restrict__ X, float* __restrict__ partials) {
  const int blk = blockIdx.x;  // [0, BATCH*NBLK)
  const int b = blk / NBLK;
  const int sub = blk % NBLK;
  const int t = threadIdx.x;
  const int c4 = t & 7;
  const int poff = t >> 3;     // 0..31
  const int ppb = HW / NBLK;   // 1152
  const int p0 = sub * ppb;

  const f32x4* base = (const f32x4*)(X + (size_t)b * HW * CH);
  f32x4 acc = {0.f, 0.f, 0.f, 0.f};
#pragma unroll 4
  for (int p = p0 + poff; p < p0 + ppb; p += 32) {
    acc += base[(size_t)p * 8 + c4];
  }

  __shared__ f32x4 sh[256];
  sh[t] = acc;
  __syncthreads();
  if (t < 8) {
    f32x4 s = {0.f, 0.f, 0.f, 0.f};
    for (int i = 0; i < 32; ++i) s += sh[i * 8 + t];
    ((f32x4*)(partials + (size_t)blk * CH))[t] = s;
  }
}

// ---------------------------------------------------------------------------
// Kernel 2: reduce partials -> feat [B,32], then theta = feat@W + b.
// ---------------------------------------------------------------------------
__global__ __launch_bounds__(512) void k_theta(
    const float* __restrict__ partials, const float* __restrict__ Wl,
    const float* __restrict__ bl, float* __restrict__ theta) {
  __shared__ float feat[BATCH * CH];  // 512
  const int t = threadIdx.x;
  {
    const int b = t >> 5, c = t & 31;
    float s = 0.f;
#pragma unroll 8
    for (int i = 0; i < NBLK; ++i)
      s += partials[((size_t)b * NBLK + i) * CH + c];
    feat[t] = s * (1.0f / (float)HW);
  }
  __syncthreads();
  if (t < BATCH * 6) {
    const int b = t / 6, j = t % 6;
    float s = bl[j];
    for (int c = 0; c < CH; ++c) s += feat[b * CH + c] * Wl[c * 6 + j];
    theta[t] = s;
  }
}

// ---------------------------------------------------------------------------
// Kernel 3: affine grid + bilinear sample, 2D-TILED pixel mapping (round-7
// structure — best measured base, 173.5us total). Block = one 8x4 output
// tile, 8 threads/pixel (c4 = t&7), wave w = tile row w. Column-major tile
// order + bijective XCD swizzle: consecutive blocks on one XCD are
// vertically adjacent -> source-row reuse stays in that XCD's L2.
// ROUND-9 A/B: NORMAL stores instead of nontemporal (single-variable test
// of the store path; everything else identical to round 7).
// Math matches reference exactly: floor -> weights from unclipped fracs,
// indices clipped to [0, 383].
// ---------------------------------------------------------------------------
__global__ __launch_bounds__(256) void k_sample(
    const float* __restrict__ X, const float* __restrict__ theta,
    float* __restrict__ out) {
  // bijective XCD swizzle (gridDim.x = 73728, divisible by 8)
  const int q = SAMP_BLOCKS >> 3;
  const int bid = blockIdx.x;
  const int blk = (bid & 7) * q + (bid >> 3);

  const int b = blk / TILES_PER_IMG;
  const int tl = blk % TILES_PER_IMG;
  const int tx = tl / TILES_Y;  // column-major: consecutive blk -> ty+1
  const int ty = tl % TILES_Y;

  const int t = threadIdx.x;
  const int c4 = t & 7;
  const int px = t >> 3;        // 0..31
  const int col = px & 7;       // 0..7
  const int row = px >> 3;      // 0..3 (== wave id)

  const int ox = tx * TILE_W + col;
  const int oy = ty * TILE_H + row;

  const float* th = theta + b * 6;
  const float gx = fmaf((float)ox, 2.0f / (float)(OUT_W - 1), -1.0f);
  const float gy = fmaf((float)oy, 2.0f / (float)(OUT_H - 1), -1.0f);
  const float sx = th[0] * gx + th[1] * gy + th[2];
  const float sy = th[3] * gx + th[4] * gy + th[5];
  const float x = (sx + 1.0f) * 0.5f * (float)(WI - 1);
  const float y = (sy + 1.0f) * 0.5f * (float)(HI - 1);

  const float x0f = floorf(x), y0f = floorf(y);
  const float wx1 = x - x0f, wx0 = 1.0f - wx1;
  const float wy1 = y - y0f, wy0 = 1.0f - wy1;
  const int x0 = min(max((int)x0f, 0), WI - 1);
  const int x1 = min(max((int)x0f + 1, 0), WI - 1);
  const int y0 = min(max((int)y0f, 0), HI - 1);
  const int y1 = min(max((int)y0f + 1, 0), HI - 1);

  const f32x4* img = (const f32x4*)(X + (size_t)b * HW * CH);
  const f32x4 g00 = img[((size_t)y0 * WI + x0) * 8 + c4];
  const f32x4 g01 = img[((size_t)y0 * WI + x1) * 8 + c4];
  const f32x4 g10 = img[((size_t)y1 * WI + x0) * 8 + c4];
  const f32x4 g11 = img[((size_t)y1 * WI + x1) * 8 + c4];

  const float w00 = wy0 * wx0, w01 = wy0 * wx1;
  const float w10 = wy1 * wx0, w11 = wy1 * wx1;

  const f32x4 r = g00 * w00 + g01 * w01 + g10 * w10 + g11 * w11;

  const size_t n = (size_t)b * (OUT_H * OUT_W) + (size_t)oy * OUT_W + ox;
  ((f32x4*)out)[n * 8 + c4] = r;  // A/B: normal (cache-allocating) store
}

extern "C" void kernel_launch(void* const* d_in, const int* in_sizes, int n_in,
                              void* d_out, int out_size, void* d_ws,
                              size_t ws_size, hipStream_t stream) {
  const float* X = (const float*)d_in[0];
  const float* Wl = (const float*)d_in[1];
  const float* bl = (const float*)d_in[2];
  float* out = (float*)d_out;

  float* partials = (float*)d_ws;                       // BATCH*NBLK*CH floats
  float* theta = partials + (size_t)BATCH * NBLK * CH;  // BATCH*6 floats

  k_partial_sums<<<BATCH * NBLK, 256, 0, stream>>>(X, partials);
  k_theta<<<1, 512, 0, stream>>>(partials, Wl, bl, theta);
  k_sample<<<SAMP_BLOCKS, 256, 0, stream>>>(X, theta, out);
}

// Round 11
// 171.923 us; speedup vs baseline: 1.3943x; 1.0625x over previous
//
#include <hip/hip_runtime.h>

#define BATCH 16
#define HI 384
#define WI 384
#define CH 32
#define OUT_H 384
#define OUT_W 384
#define HW (HI * WI)
#define NBLK 128                       // partial-sum blocks per batch image
#define TILE_W 8
#define TILE_H 4
#define TILES_X (OUT_W / TILE_W)       // 48
#define TILES_Y (OUT_H / TILE_H)       // 96
#define TILES_PER_IMG (TILES_X * TILES_Y)       // 4608
#define SAMP_BLOCKS (BATCH * TILES_PER_IMG)     // 73728, divisible by 8

typedef float f32x4 __attribute__((ext_vector_type(4)));

// ---------------------------------------------------------------------------
// Kernel 1: per-(batch, slice) partial sums (mean pass). No atomics,
// deterministic; block reads contiguous 4KB chunks; 8 blocks/CU.
// Normal (cache-allocating) loads on purpose: leaves X warm in L2/L3 for the
// gather phase (round-5/9 counters: gather HBM fetch only ~147MB of 1.2GB
// requested).
// ---------------------------------------------------------------------------
__global__ __launch_bounds__(256) void k_partial_sums(
    const float* __restrict__ X, float* __restrict__ partials) {
  const int blk = blockIdx.x;  // [0, BATCH*NBLK)
  const int b = blk / NBLK;
  const int sub = blk % NBLK;
  const int t = threadIdx.x;
  const int c4 = t & 7;
  const int poff = t >> 3;     // 0..31
  const int ppb = HW / NBLK;   // 1152
  const int p0 = sub * ppb;

  const f32x4* base = (const f32x4*)(X + (size_t)b * HW * CH);
  f32x4 acc = {0.f, 0.f, 0.f, 0.f};
#pragma unroll 4
  for (int p = p0 + poff; p < p0 + ppb; p += 32) {
    acc += base[(size_t)p * 8 + c4];
  }

  __shared__ f32x4 sh[256];
  sh[t] = acc;
  __syncthreads();
  if (t < 8) {
    f32x4 s = {0.f, 0.f, 0.f, 0.f};
    for (int i = 0; i < 32; ++i) s += sh[i * 8 + t];
    ((f32x4*)(partials + (size_t)blk * CH))[t] = s;
  }
}

// ---------------------------------------------------------------------------
// Kernel 2: reduce partials -> feat [B,32], then theta = feat@W + b.
// ---------------------------------------------------------------------------
__global__ __launch_bounds__(512) void k_theta(
    const float* __restrict__ partials, const float* __restrict__ Wl,
    const float* __restrict__ bl, float* __restrict__ theta) {
  __shared__ float feat[BATCH * CH];  // 512
  const int t = threadIdx.x;
  {
    const int b = t >> 5, c = t & 31;
    float s = 0.f;
#pragma unroll 8
    for (int i = 0; i < NBLK; ++i)
      s += partials[((size_t)b * NBLK + i) * CH + c];
    feat[t] = s * (1.0f / (float)HW);
  }
  __syncthreads();
  if (t < BATCH * 6) {
    const int b = t / 6, j = t % 6;
    float s = bl[j];
    for (int c = 0; c < CH; ++c) s += feat[b * CH + c] * Wl[c * 6 + j];
    theta[t] = s;
  }
}

// ---------------------------------------------------------------------------
// Kernel 3: affine grid + bilinear sample — round-7 verified-best structure.
// Block = one 8x4 output tile, 8 threads/pixel (c4 = t&7), wave w = tile
// row w: vertical tap reuse (row r's y1 rows == row r+1's y0 rows) is
// captured by co-resident waves via L1. Column-major tile order + bijective
// XCD swizzle: consecutive blocks on one XCD are vertically adjacent ->
// source-row reuse stays in that XCD's L2.
// NT stores (A/B-verified round 10: +9us vs normal — keeps L2/L3 for the
// gather working set). Per-wave coalescing: each tap load = 8px x 128B
// segments; store = 1KB contiguous.
// Math matches reference exactly: floor -> weights from unclipped fracs,
// indices clipped to [0, 383].
// ---------------------------------------------------------------------------
__global__ __launch_bounds__(256) void k_sample(
    const float* __restrict__ X, const float* __restrict__ theta,
    float* __restrict__ out) {
  // bijective XCD swizzle (gridDim.x = 73728, divisible by 8)
  const int q = SAMP_BLOCKS >> 3;
  const int bid = blockIdx.x;
  const int blk = (bid & 7) * q + (bid >> 3);

  const int b = blk / TILES_PER_IMG;
  const int tl = blk % TILES_PER_IMG;
  const int tx = tl / TILES_Y;  // column-major: consecutive blk -> ty+1
  const int ty = tl % TILES_Y;

  const int t = threadIdx.x;
  const int c4 = t & 7;
  const int px = t >> 3;        // 0..31
  const int col = px & 7;       // 0..7
  const int row = px >> 3;      // 0..3 (== wave id)

  const int ox = tx * TILE_W + col;
  const int oy = ty * TILE_H + row;

  const float* th = theta + b * 6;
  const float gx = fmaf((float)ox, 2.0f / (float)(OUT_W - 1), -1.0f);
  const float gy = fmaf((float)oy, 2.0f / (float)(OUT_H - 1), -1.0f);
  const float sx = th[0] * gx + th[1] * gy + th[2];
  const float sy = th[3] * gx + th[4] * gy + th[5];
  const float x = (sx + 1.0f) * 0.5f * (float)(WI - 1);
  const float y = (sy + 1.0f) * 0.5f * (float)(HI - 1);

  const float x0f = floorf(x), y0f = floorf(y);
  const float wx1 = x - x0f, wx0 = 1.0f - wx1;
  const float wy1 = y - y0f, wy0 = 1.0f - wy1;
  const int x0 = min(max((int)x0f, 0), WI - 1);
  const int x1 = min(max((int)x0f + 1, 0), WI - 1);
  const int y0 = min(max((int)y0f, 0), HI - 1);
  const int y1 = min(max((int)y0f + 1, 0), HI - 1);

  const f32x4* img = (const f32x4*)(X + (size_t)b * HW * CH);
  const f32x4 g00 = img[((size_t)y0 * WI + x0) * 8 + c4];
  const f32x4 g01 = img[((size_t)y0 * WI + x1) * 8 + c4];
  const f32x4 g10 = img[((size_t)y1 * WI + x0) * 8 + c4];
  const f32x4 g11 = img[((size_t)y1 * WI + x1) * 8 + c4];

  const float w00 = wy0 * wx0, w01 = wy0 * wx1;
  const float w10 = wy1 * wx0, w11 = wy1 * wx1;

  const f32x4 r = g00 * w00 + g01 * w01 + g10 * w10 + g11 * w11;

  const size_t n = (size_t)b * (OUT_H * OUT_W) + (size_t)oy * OUT_W + ox;
  __builtin_nontemporal_store(r, (f32x4*)out + n * 8 + c4);
}

extern "C" void kernel_launch(void* const* d_in, const int* in_sizes, int n_in,
                              void* d_out, int out_size, void* d_ws,
                              size_t ws_size, hipStream_t stream) {
  const float* X = (const float*)d_in[0];
  const float* Wl = (const float*)d_in[1];
  const float* bl = (const float*)d_in[2];
  float* out = (float*)d_out;

  float* partials = (float*)d_ws;                       // BATCH*NBLK*CH floats
  float* theta = partials + (size_t)BATCH * NBLK * CH;  // BATCH*6 floats

  k_partial_sums<<<BATCH * NBLK, 256, 0, stream>>>(X, partials);
  k_theta<<<1, 512, 0, stream>>>(partials, Wl, bl, theta);
  k_sample<<<SAMP_BLOCKS, 256, 0, stream>>>(X, theta, out);
}